// Round 1
// baseline (191.483 us; speedup 1.0000x reference)
//
#include <hip/hip_runtime.h>

// RadarSparseProcessor: out[v,o] = (sum_p sum_c F[v,p,c]*W[o,c]) / max(n[v],1)
// V=1048576, P=4, C_IN=4, C_OUT=32.
//
// R6: theory — measured dur_us is ~2x 512MiB harness poison fills (82us each)
// + ~26us of actual kernel (kernel absent from rocprof top-5 despite
// dur_us=190 > 82 -> kernel itself runs <78us under profiling; 82+82+26=190).
// Kernel-side roofline: 196 MiB traffic -> 31us @ 6.3TB/s HBM, less with L3
// residency (total working set 196 MiB < 256 MiB Infinity Cache).
// The one remaining kernel-side lever: the feat loads were NONTEMPORAL,
// which deprioritizes L2/L3 residency and forces the 64 MiB input stream to
// HBM every iteration even though it is L3-resident across bench iterations.
// Drop nt -> feat reads become Infinity-Cache hits.
//  - stores stay CACHED (L2 write-allocate merges into full 128B lines).
//  - 1/n via __builtin_amdgcn_rcpf (n in {1..4}).

typedef float vf4 __attribute__((ext_vector_type(4)));

__device__ __forceinline__ void load_w(const vf4* __restrict__ Wf4, int q, vf4* w) {
#pragma unroll
    for (int j = 0; j < 4; ++j) w[j]     = Wf4[q * 4 + j];
#pragma unroll
    for (int j = 0; j < 4; ++j) w[4 + j] = Wf4[16 + q * 4 + j];
}

__device__ __forceinline__ void voxel_body(vf4 p, int n, const vf4* w,
                                           vf4* __restrict__ ob, size_t v, int q) {
    // butterfly sum over the 4 points (lanes q^1, q^2 stay in-group)
    p.x += __shfl_xor(p.x, 1); p.y += __shfl_xor(p.y, 1);
    p.z += __shfl_xor(p.z, 1); p.w += __shfl_xor(p.w, 1);
    p.x += __shfl_xor(p.x, 2); p.y += __shfl_xor(p.y, 2);
    p.z += __shfl_xor(p.z, 2); p.w += __shfl_xor(p.w, 2);

    float inv = __builtin_amdgcn_rcpf((float)(n > 1 ? n : 1));

    vf4 o0, o1;
    o0.x = (p.x*w[0].x + p.y*w[0].y + p.z*w[0].z + p.w*w[0].w) * inv;
    o0.y = (p.x*w[1].x + p.y*w[1].y + p.z*w[1].z + p.w*w[1].w) * inv;
    o0.z = (p.x*w[2].x + p.y*w[2].y + p.z*w[2].z + p.w*w[2].w) * inv;
    o0.w = (p.x*w[3].x + p.y*w[3].y + p.z*w[3].z + p.w*w[3].w) * inv;
    o1.x = (p.x*w[4].x + p.y*w[4].y + p.z*w[4].z + p.w*w[4].w) * inv;
    o1.y = (p.x*w[5].x + p.y*w[5].y + p.z*w[5].z + p.w*w[5].w) * inv;
    o1.z = (p.x*w[6].x + p.y*w[6].y + p.z*w[6].z + p.w*w[6].w) * inv;
    o1.w = (p.x*w[7].x + p.y*w[7].y + p.z*w[7].z + p.w*w[7].w) * inv;

    // lane q covers bytes [64q/4..), full 64B sectors per inst
    ob[v * 8 + q]     = o0;
    ob[v * 8 + 4 + q] = o1;
}

// Specialized: V == 1048576, grid == 2048x256 -> exactly 8 voxels/thread.
__global__ __launch_bounds__(256) void radar_pointnet_v8(
    const float* __restrict__ feat, const float* __restrict__ Wm,
    const int* __restrict__ npts, float* __restrict__ out)
{
    constexpr int NG = 131072;                    // voxel-groups in grid
    const int tid = blockIdx.x * 256 + threadIdx.x;
    const int q   = tid & 3;
    const int g0  = tid >> 2;

    vf4 w[8];
    load_w((const vf4*)Wm, q, w);

    const vf4* __restrict__ f4 = (const vf4*)feat;
    vf4* __restrict__ ob = (vf4*)out;

    vf4 p[8];
    int n[8];
#pragma unroll
    for (int k = 0; k < 8; ++k) {                 // all 16 loads issue up front
        size_t v = (size_t)g0 + (size_t)k * NG;
        p[k] = f4[v * 4 + q];                     // R6: cached (was nontemporal)
        n[k] = npts[v];
    }
#pragma unroll
    for (int k = 0; k < 8; ++k) {
        size_t v = (size_t)g0 + (size_t)k * NG;
        voxel_body(p[k], n[k], w, ob, v, q);
    }
}

// Generic fallback (any V).
__global__ __launch_bounds__(256) void radar_pointnet_gen(
    const float* __restrict__ feat, const float* __restrict__ Wm,
    const int* __restrict__ npts, float* __restrict__ out, int V)
{
    const int tid = blockIdx.x * blockDim.x + threadIdx.x;
    const int q   = tid & 3;
    const int g0  = tid >> 2;
    const int ngroups = (gridDim.x * blockDim.x) >> 2;

    vf4 w[8];
    load_w((const vf4*)Wm, q, w);

    const vf4* __restrict__ f4 = (const vf4*)feat;
    vf4* __restrict__ ob = (vf4*)out;

    for (int v = g0; v < V; v += ngroups) {
        vf4 p = f4[(size_t)v * 4 + q];            // R6: cached (was nontemporal)
        voxel_body(p, npts[v], w, ob, (size_t)v, q);
    }
}

extern "C" void kernel_launch(void* const* d_in, const int* in_sizes, int n_in,
                              void* d_out, int out_size, void* d_ws, size_t ws_size,
                              hipStream_t stream) {
    const float* feat = (const float*)d_in[0];   // [V,4,4]
    const float* Wm   = (const float*)d_in[1];   // [32,4]
    const int*   np   = (const int*)d_in[2];     // [V]
    float*       out  = (float*)d_out;           // [V,32]

    int V = in_sizes[0] / 16;                    // P*C_IN = 16 floats per voxel

    if (V == 1048576) {
        radar_pointnet_v8<<<2048, 256, 0, stream>>>(feat, Wm, np, out);
    } else {
        int block = 256;
        int grid  = 2048;
        int max_grid = (V * 4 + block - 1) / block;
        if (grid > max_grid) grid = max_grid;
        if (grid < 1) grid = 1;
        radar_pointnet_gen<<<grid, block, 0, stream>>>(feat, Wm, np, out, V);
    }
}